// Round 7
// baseline (979.544 us; speedup 1.0000x reference)
//
#include <hip/hip_runtime.h>
#include <hip/hip_bf16.h>

// ---------- types ----------
typedef _Float16 h16;
typedef h16   h16x8 __attribute__((ext_vector_type(8)));
typedef h16   h16x4 __attribute__((ext_vector_type(4)));
typedef float f32x4 __attribute__((ext_vector_type(4)));
typedef float f32x16 __attribute__((ext_vector_type(16)));

#define EMB 1024
#define ED4 4096L   // EMB*4 flattened feature dim

// ---------- async global->LDS (16B per lane, wave-uniform LDS base) ----------
__device__ __forceinline__ void gload_lds16(const void* g, void* l) {
    __builtin_amdgcn_global_load_lds(
        (__attribute__((address_space(1))) void*)g,
        (__attribute__((address_space(3))) void*)l,
        16, 0, 0);
}

// ---------- build effective block weight M[o*4+q][i*4+c] = s(q,c)*W[q^c][o][i], fp16 ----------
__global__ __launch_bounds__(256) void k_build_m(const float* __restrict__ W, h16* __restrict__ M) {
    int t = blockIdx.x * 256 + threadIdx.x;   // [0, 4096*1024)
    int i = t & 1023;
    int n = t >> 10;          // o*4+q
    int o = n >> 2, q = n & 3;
    // sign masks per q (bit c set => negative): q0:0xE q1:0x8 q2:0x2 q3:0x4
    unsigned packed = 0xEu | (0x8u << 4) | (0x2u << 8) | (0x4u << 12);
    unsigned sm = (packed >> (q * 4)) & 0xFu;
    h16x4 out;
#pragma unroll
    for (int c = 0; c < 4; ++c) {
        int d = q ^ c;
        float w = W[((long)d * EMB + o) * EMB + i];
        out[c] = (h16)(((sm >> c) & 1u) ? -w : w);
    }
    *(h16x4*)&M[(long)n * ED4 + i * 4] = out;
}

// ---------- fp32 -> fp16 convert (x inputs), 4 elems/thread ----------
__global__ __launch_bounds__(256) void k_f32_to_f16(const float* __restrict__ in, h16* __restrict__ out) {
    long i = ((long)blockIdx.x * 256 + threadIdx.x) * 4;
    float4 v = *(const float4*)(in + i);
    h16x4 o;
    o[0] = (h16)v.x; o[1] = (h16)v.y; o[2] = (h16)v.z; o[3] = (h16)v.w;
    *(h16x4*)(out + i) = o;
}

// =====================================================================
// 256x256-tile, BK=64, 4-phase GEMM with 32x32x16 MFMA (4096^3 only)
// C[m][n] = sum_k A[m][k]*B[n][k] + bias[n]
// 512 threads = 8 waves. Each PHASE computes one GLOBAL 128x128 C-quadrant
// (mh, nh); waves tile it 2x4 (per-wave 64x32 = 2 frags of 32x32,
// 8 MFMA of 32x32x16 over K=64).
//   ph1 (0,0): ds_read A(8)+B0(4)   stage (t+1).A1
//   ph2 (0,1): ds_read B1(4)        stage (t+1).B1   [A frags kept in regs]
//   ph3 (1,0): ds_read A1(8)        stage (t+2).A0   [B0 kept in regs]
//   ph4 (1,1): no ds_reads          stage (t+2).B0 ; vmcnt(4)
// Ledger identical to round-6 green kernel (stage target's last ds_read is
// >=1 barrier + chip-wide lgkmcnt(0) behind; vmcnt(4) at ph4 guarantees
// tile t+1 fully landed; never drains to 0 in-loop).
// XCD swizzle (T1): nwg=256 % 8 == 0, chunked bijective remap so each XCD
// gets 2 consecutive N-panel rows (4MB B in its L2).
// MFMA 32x32x16 layouts: A/B row|col = lane&31, k = (lane>>5)*8 + j;
// C/D col = lane&31, row = (reg&3) + 8*(reg>>2) + 4*(lane>>5)  [m74/m101].
// =====================================================================
#define BAR() __builtin_amdgcn_s_barrier()
#define LGKM0() do { asm volatile("s_waitcnt lgkmcnt(0)" ::: "memory"); \
                     __builtin_amdgcn_sched_barrier(0); } while (0)
#define STAGE(matv, basev, row0v, tt, hh) do { \
    const h16* _src = (basev) + ((row0v) + (hh) * 128L) * 4096L + (long)(tt) * 64 + scol; \
    h16* _dst = &lds[(((tt) & 1) << 15) + (matv) * 16384 + (hh) * 8192 + w * 512]; \
    gload_lds16(_src, _dst); \
    gload_lds16(_src + 64 * 4096L, _dst + 4096); \
} while (0)
// A frag (half mh, row-frag mf, k-step ks): rows wm*64+mf*32+l31, 16B slot (ks*2+lhi)^l7
#define LDA32(mh, mf, ks) (*(const h16x8*)&lds[cbuf + (mh) * 8192 + (wm * 64 + (mf) * 32 + l31) * 64 + ((((ks) * 2 + lhi) ^ l7) << 3)])
#define LDB32(nh, ks)     (*(const h16x8*)&lds[cbuf + 16384 + (nh) * 8192 + (wn * 32 + l31) * 64 + ((((ks) * 2 + lhi) ^ l7) << 3)])
#define MFMA_Q32(MH, NH, BF) do { \
    __builtin_amdgcn_s_setprio(1); \
    _Pragma("unroll") \
    for (int ks = 0; ks < 4; ++ks) \
        _Pragma("unroll") \
        for (int mf = 0; mf < 2; ++mf) \
            acc[MH][NH][mf] = __builtin_amdgcn_mfma_f32_32x32x16_f16(af[mf][ks], BF[ks], acc[MH][NH][mf], 0, 0, 0); \
    __builtin_amdgcn_s_setprio(0); \
} while (0)

template <typename OUT_T>
__global__ __launch_bounds__(512, 2) void k_gemm256(
    const h16* __restrict__ A, const h16* __restrict__ B,
    OUT_T* __restrict__ C, const float* __restrict__ bias, int nt)
{
    __shared__ __align__(16) h16 lds[65536];   // 128 KiB

    const int tid = threadIdx.x;
    const int w  = tid >> 6, l = tid & 63;
    const int wm = w >> 2, wn = w & 3;          // wave grid 2x4 within each quadrant
    const int l31 = l & 31, lhi = l >> 5, l7 = l & 7;

    // XCD-chunked bijective block swizzle (dispatch id -> tile coords)
    const int wid0 = blockIdx.y * 16 + blockIdx.x;
    const int wid  = (wid0 & 7) * 32 + (wid0 >> 3);
    const int tx = wid & 15, ty = wid >> 4;

    // staging: thread covers 16B; srow in [0,64) per gload, swizzled col
    const int srow = w * 8 + (l >> 3);
    const int scol = ((l & 7) ^ ((l >> 3) & 7)) << 3;
    const long arow0 = (long)tx * 256 + srow;
    const long brow0 = (long)ty * 256 + srow;

    f32x16 acc[2][2][2] = {};   // [mh][nh][mf]

    // prologue: 0.A0 0.B0 0.A1 0.B1 1.A0 1.B0 (12 loads); vmcnt(4) -> tile0 landed
    STAGE(0, A, arow0, 0, 0);
    STAGE(1, B, brow0, 0, 0);
    STAGE(0, A, arow0, 0, 1);
    STAGE(1, B, brow0, 0, 1);
    STAGE(0, A, arow0, 1, 0);
    STAGE(1, B, brow0, 1, 0);
    asm volatile("s_waitcnt vmcnt(4)" ::: "memory");
    __builtin_amdgcn_sched_barrier(0);
    BAR();

    for (int t = 0; t < nt; ++t) {
        const int cbuf = (t & 1) << 15;
        h16x8 af[2][4], b0[4], b1[4];

        // ---- phase 1: quadrant (0,0) — load A-half0 + B0; stage (t+1).A1 ----
#pragma unroll
        for (int mf = 0; mf < 2; ++mf)
#pragma unroll
            for (int ks = 0; ks < 4; ++ks) af[mf][ks] = LDA32(0, mf, ks);
#pragma unroll
        for (int ks = 0; ks < 4; ++ks) b0[ks] = LDB32(0, ks);
        if (t + 1 < nt) STAGE(0, A, arow0, t + 1, 1);
        BAR(); LGKM0();
        MFMA_Q32(0, 0, b0);
        BAR();

        // ---- phase 2: quadrant (0,1) — load B1; stage (t+1).B1 ----
#pragma unroll
        for (int ks = 0; ks < 4; ++ks) b1[ks] = LDB32(1, ks);
        if (t + 1 < nt) STAGE(1, B, brow0, t + 1, 1);
        BAR(); LGKM0();
        MFMA_Q32(0, 1, b1);
        BAR();

        // ---- phase 3: quadrant (1,0) — load A-half1; stage (t+2).A0 ----
#pragma unroll
        for (int mf = 0; mf < 2; ++mf)
#pragma unroll
            for (int ks = 0; ks < 4; ++ks) af[mf][ks] = LDA32(1, mf, ks);
        if (t + 2 < nt) STAGE(0, A, arow0, t + 2, 0);
        BAR(); LGKM0();
        MFMA_Q32(1, 0, b0);
        BAR();

        // ---- phase 4: quadrant (1,1) — no ds_reads; stage (t+2).B0; drain ----
        if (t + 2 < nt) STAGE(1, B, brow0, t + 2, 0);
        if (t < nt - 2) { asm volatile("s_waitcnt vmcnt(4)" ::: "memory"); }
        else            { asm volatile("s_waitcnt vmcnt(0)" ::: "memory"); }
        __builtin_amdgcn_sched_barrier(0);
        BAR();
        MFMA_Q32(1, 1, b1);
        BAR();
    }

    // epilogue (32x32 C/D layout): row = tx*256 + mh*128 + wm*64 + mf*32
    //   + (j&3) + 8*(j>>2) + 4*lhi ;  col = ty*256 + nh*128 + wn*32 + l31
    const long rb  = (long)tx * 256 + wm * 64 + 4 * lhi;
    const int  cb0 = ty * 256 + wn * 32 + l31;
#pragma unroll
    for (int mh = 0; mh < 2; ++mh)
#pragma unroll
        for (int nh = 0; nh < 2; ++nh) {
            const int col = cb0 + nh * 128;
            const float bv = bias[col];
#pragma unroll
            for (int mf = 0; mf < 2; ++mf) {
                const long r0 = rb + mh * 128 + mf * 32;
#pragma unroll
                for (int j = 0; j < 16; ++j) {
                    const long row = r0 + (j & 3) + 8 * (j >> 2);
                    C[row * 4096L + col] = (OUT_T)(acc[mh][nh][mf][j] + bv);
                }
            }
        }
}

// ---------- GEMM: C[m][n] = alpha * sum_k A[m][k]*B[n][k] (+ bias[n]) ----------
// 128x128 tile, BK=32 (m97 structure) — used for the attention GEMMs.
template <typename OUT_T, bool HAS_BIAS>
__global__ __launch_bounds__(256) void k_gemm_bt(
    const h16* __restrict__ A, const h16* __restrict__ B,
    OUT_T* __restrict__ C, const float* __restrict__ bias,
    int lda, int ldb, int ldc,
    long sAb, long sAh, long sBb, long sBh, long sCb, long sCh,
    float alpha, int kIters)
{
    __shared__ __align__(16) h16 As[128 * 32];
    __shared__ __align__(16) h16 Bs[128 * 32];

    const int z = blockIdx.z, zb = z >> 4, zh = z & 15;
    const h16* Ab = A + zb * sAb + zh * sAh + (long)blockIdx.x * 128 * lda;
    const h16* Bb = B + zb * sBb + zh * sBh + (long)blockIdx.y * 128 * ldb;

    const int tid = threadIdx.x, w = tid >> 6, lane = tid & 63;
    const int wr = (w >> 1) * 64, wc = (w & 1) * 64;
    const int scol = (lane & 3) * 8;
    const int srow = lane >> 2;
    const int koff = (lane >> 4) * 8;
    const int fr   = lane & 15;

    f32x4 acc[4][4] = {};

    for (int kt = 0; kt < kIters; ++kt) {
        const int k0 = kt * 32;
#pragma unroll
        for (int j = 0; j < 2; ++j) {
            const int ca  = w * 2 + j;
            const int row = ca * 16 + srow;
            gload_lds16(Ab + (long)row * lda + k0 + scol, &As[ca * 512]);
            gload_lds16(Bb + (long)row * ldb + k0 + scol, &Bs[ca * 512]);
        }
        __syncthreads();

        h16x8 af[4], bfr[4];
#pragma unroll
        for (int m = 0; m < 4; ++m)
            af[m] = *(const h16x8*)&As[(wr + m * 16 + fr) * 32 + koff];
#pragma unroll
        for (int n = 0; n < 4; ++n)
            bfr[n] = *(const h16x8*)&Bs[(wc + n * 16 + fr) * 32 + koff];
        __syncthreads();

#pragma unroll
        for (int m = 0; m < 4; ++m)
#pragma unroll
            for (int n = 0; n < 4; ++n)
                acc[m][n] = __builtin_amdgcn_mfma_f32_16x16x32_f16(af[m], bfr[n], acc[m][n], 0, 0, 0);
    }

    OUT_T* Cb = C + zb * sCb + zh * sCh;
    const long rbase = (long)blockIdx.x * 128 + wr + (lane >> 4) * 4;
    const int  cbase = blockIdx.y * 128 + wc + fr;
#pragma unroll
    for (int n = 0; n < 4; ++n) {
        const int col = cbase + n * 16;
        const float bv = HAS_BIAS ? bias[col] : 0.0f;
#pragma unroll
        for (int m = 0; m < 4; ++m) {
            const long row0 = rbase + m * 16;
#pragma unroll
            for (int j = 0; j < 4; ++j) {
                float vv = acc[m][n][j] * alpha + bv;
                Cb[(row0 + j) * ldc + col] = (OUT_T)vv;
            }
        }
    }
}

// ---------- transpose V slice: Vt[z][f][t] = Vb[b*1024+t][h*256+f], fp16 ----------
__global__ void k_transpose_v(const h16* __restrict__ Vb, h16* __restrict__ Vt) {
    __shared__ h16 tile[32][34];
    const int z = blockIdx.z, b = z >> 4, h = z & 15;
    const int f0 = blockIdx.x * 32, t0 = blockIdx.y * 32;
    const int tx = threadIdx.x, ty = threadIdx.y;   // 32 x 8
#pragma unroll
    for (int j = 0; j < 4; ++j)
        tile[ty + 8 * j][tx] = Vb[(long)(b * 1024 + t0 + ty + 8 * j) * ED4 + h * 256 + f0 + tx];
    __syncthreads();
#pragma unroll
    for (int j = 0; j < 4; ++j)
        Vt[(long)z * (256 * 1024) + (long)(f0 + ty + 8 * j) * 1024 + t0 + tx] = tile[tx][ty + 8 * j];
}

// ---------- row softmax over S[row][1024] fp16 in place ----------
__global__ __launch_bounds__(256) void k_softmax(h16* __restrict__ S) {
    const long row = blockIdx.x;
    h16* p = S + row * 1024;
    const int tid = threadIdx.x, w = tid >> 6, lane = tid & 63;
    h16x4 xi = *(const h16x4*)&p[tid * 4];
    float x[4];
#pragma unroll
    for (int j = 0; j < 4; ++j) x[j] = (float)xi[j];
    float m = fmaxf(fmaxf(x[0], x[1]), fmaxf(x[2], x[3]));
#pragma unroll
    for (int off = 32; off; off >>= 1) m = fmaxf(m, __shfl_xor(m, off));
    __shared__ float red[8];
    if (lane == 0) red[w] = m;
    __syncthreads();
    m = fmaxf(fmaxf(red[0], red[1]), fmaxf(red[2], red[3]));
    float s = 0.0f;
#pragma unroll
    for (int j = 0; j < 4; ++j) { x[j] = __expf(x[j] - m); s += x[j]; }
#pragma unroll
    for (int off = 32; off; off >>= 1) s += __shfl_xor(s, off);
    if (lane == 0) red[4 + w] = s;
    __syncthreads();
    s = red[4] + red[5] + red[6] + red[7];
    const float inv = 1.0f / s;
    h16x4 o;
#pragma unroll
    for (int j = 0; j < 4; ++j) o[j] = (h16)(x[j] * inv);
    *(h16x4*)&p[tid * 4] = o;
}

// ---------- launch ----------
extern "C" void kernel_launch(void* const* d_in, const int* in_sizes, int n_in,
                              void* d_out, int out_size, void* d_ws, size_t ws_size,
                              hipStream_t stream) {
    const float* q  = (const float*)d_in[0];
    const float* k  = (const float*)d_in[1];
    const float* v  = (const float*)d_in[2];
    const float* Wq = (const float*)d_in[3];
    const float* bq = (const float*)d_in[4];
    const float* Wk = (const float*)d_in[5];
    const float* bk = (const float*)d_in[6];
    const float* Wv = (const float*)d_in[7];
    const float* bv = (const float*)d_in[8];
    const float* Wo = (const float*)d_in[9];
    const float* bo = (const float*)d_in[10];
    float* out = (float*)d_out;

    // workspace layout: 256 MB total (X and M slots are time-shared; scores
    // buffer is chunked per batch, 16 heads x 1024 x 1024 fp16 = 32 MB).
    char* ws = (char*)d_ws;
    const long MB = 1024L * 1024;
    h16* X  = (h16*)(ws + 0 * MB);     // 32 MB: converted q/k/v input (serial)
    h16* M  = (h16*)(ws + 32 * MB);    // 32 MB: effective weight (serial)
    h16* Qb = (h16*)(ws + 64 * MB);
    h16* Kb = (h16*)(ws + 96 * MB);
    h16* Vb = (h16*)(ws + 128 * MB);
    h16* Vt = (h16*)(ws + 160 * MB);
    h16* AO = (h16*)(ws + 192 * MB);
    h16* Sc = (h16*)(ws + 224 * MB);   // 32 MB score chunk (one batch, 16 heads)

    dim3 blk(256);
    dim3 g256(16, 16, 1);

    // Q projection: convert, build weight, GEMM (serially reusing X, M)
    k_f32_to_f16<<<16384, blk, 0, stream>>>(q, X);
    k_build_m<<<16384, blk, 0, stream>>>(Wq, M);
    k_gemm256<h16><<<g256, 512, 0, stream>>>(X, M, Qb, bq, 64);

    // K projection
    k_f32_to_f16<<<16384, blk, 0, stream>>>(k, X);
    k_build_m<<<16384, blk, 0, stream>>>(Wk, M);
    k_gemm256<h16><<<g256, 512, 0, stream>>>(X, M, Kb, bk, 64);

    // V projection
    k_f32_to_f16<<<16384, blk, 0, stream>>>(v, X);
    k_build_m<<<16384, blk, 0, stream>>>(Wv, M);
    k_gemm256<h16><<<g256, 512, 0, stream>>>(X, M, Vb, bv, 64);

    // V transpose per (b,h): Vt[z][256][1024]
    k_transpose_v<<<dim3(8, 32, 64), dim3(32, 8), 0, stream>>>(Vb, Vt);

    // attention, one batch (16 heads) at a time through the 32 MB score chunk
    for (int c = 0; c < 4; ++c) {
        const h16* Qc  = Qb + (long)c * 1024 * 4096;
        const h16* Kc  = Kb + (long)c * 1024 * 4096;
        const h16* VtC = Vt + (long)c * 16 * 256 * 1024;
        h16*       AOc = AO + (long)c * 1024 * 4096;

        // scores: Sc[zh][1024][1024] = (Q K^T)/16, fp16
        k_gemm_bt<h16, false><<<dim3(8, 8, 16), blk, 0, stream>>>(
            Qc, Kc, Sc, nullptr,
            4096, 4096, 1024,
            0, 256,                       // A: h-stride (256-col slices)
            0, 256,                       // B
            0, 1024L * 1024,              // C
            0.0625f, 8);

        // softmax rows in place (fp16)
        k_softmax<<<16384, blk, 0, stream>>>(Sc);

        // attn out: AOc[t][h*256+f] = P_zh . Vt_zh^T
        k_gemm_bt<h16, false><<<dim3(8, 2, 16), blk, 0, stream>>>(
            Sc, VtC, AOc, nullptr,
            1024, 1024, 4096,
            0, 1024L * 1024,              // A
            0, 256L * 1024,               // B
            0, 256,                       // C
            1.0f, 32);
    }

    // output projection: out = AO . Mo^T + bo (fp32 out)
    k_build_m<<<16384, blk, 0, stream>>>(Wo, M);
    k_gemm256<float><<<g256, 512, 0, stream>>>(AO, M, out, bo, 64);
}

// Round 8
// 962.534 us; speedup vs baseline: 1.0177x; 1.0177x over previous
//
#include <hip/hip_runtime.h>
#include <hip/hip_bf16.h>

// ---------- types ----------
typedef _Float16 h16;
typedef h16   h16x8 __attribute__((ext_vector_type(8)));
typedef h16   h16x4 __attribute__((ext_vector_type(4)));
typedef float f32x4 __attribute__((ext_vector_type(4)));
typedef float f32x16 __attribute__((ext_vector_type(16)));

#define EMB 1024
#define ED4 4096L   // EMB*4 flattened feature dim

// ---------- async global->LDS (16B per lane, wave-uniform LDS base) ----------
__device__ __forceinline__ void gload_lds16(const void* g, void* l) {
    __builtin_amdgcn_global_load_lds(
        (__attribute__((address_space(1))) void*)g,
        (__attribute__((address_space(3))) void*)l,
        16, 0, 0);
}

// ---------- build effective block weight M[o*4+q][i*4+c] = s(q,c)*W[q^c][o][i], fp16 ----------
__global__ __launch_bounds__(256) void k_build_m(const float* __restrict__ W, h16* __restrict__ M) {
    int t = blockIdx.x * 256 + threadIdx.x;   // [0, 4096*1024)
    int i = t & 1023;
    int n = t >> 10;          // o*4+q
    int o = n >> 2, q = n & 3;
    // sign masks per q (bit c set => negative): q0:0xE q1:0x8 q2:0x2 q3:0x4
    unsigned packed = 0xEu | (0x8u << 4) | (0x2u << 8) | (0x4u << 12);
    unsigned sm = (packed >> (q * 4)) & 0xFu;
    h16x4 out;
#pragma unroll
    for (int c = 0; c < 4; ++c) {
        int d = q ^ c;
        float w = W[((long)d * EMB + o) * EMB + i];
        out[c] = (h16)(((sm >> c) & 1u) ? -w : w);
    }
    *(h16x4*)&M[(long)n * ED4 + i * 4] = out;
}

// ---------- fp32 -> fp16 convert (x inputs), 4 elems/thread ----------
__global__ __launch_bounds__(256) void k_f32_to_f16(const float* __restrict__ in, h16* __restrict__ out) {
    long i = ((long)blockIdx.x * 256 + threadIdx.x) * 4;
    float4 v = *(const float4*)(in + i);
    h16x4 o;
    o[0] = (h16)v.x; o[1] = (h16)v.y; o[2] = (h16)v.z; o[3] = (h16)v.w;
    *(h16x4*)(out + i) = o;
}

// =====================================================================
// 256x256-tile, BK=64, 4-phase GEMM with 32x32x16 MFMA (4096^3 only)
// C[m][n] = sum_k A[m][k]*B[n][k] + bias[n]
// 512 threads = 8 waves. Each PHASE computes one GLOBAL 128x128 C-quadrant
// (mh, nh); waves tile it 2x4 (per-wave 64x32 = 2 frags of 32x32,
// 8 MFMA of 32x32x16 over K=64).
//   ph1 (0,0): ds_read A(8)+B0(4)   stage (t+1).A1
//   ph2 (0,1): ds_read B1(4)        stage (t+1).B1   [A frags kept in regs]
//   ph3 (1,0): ds_read A1(8)        stage (t+2).A0   [B0 kept in regs]
//   ph4 (1,1): no ds_reads          stage (t+2).B0 ; vmcnt(4)
// Ledger identical to round-6 green kernel (stage target's last ds_read is
// >=1 barrier + chip-wide lgkmcnt(0) behind; vmcnt(4) at ph4 guarantees
// tile t+1 fully landed; never drains to 0 in-loop).
//
// Swizzle (bank-conflict fix, r8): LDS(r, s) holds global 16B-slot
//   s ^ (r&7) ^ ((r>>3)&1).
// Store side: staged chunk has r>>3 == w (and w+8 for the +64-row gload,
// same parity), so global source slot = (l&7) ^ ((l>>3)&7) ^ (w&1).
// Read side: fragment rows are base(l31-aligned)+l31 -> LDS slot =
//   (2ks+lhi) ^ (l&7) ^ ((l>>3)&1).
// The extra ((l>>3)&1) term varies within 16-lane groups, restoring the
// conflict-free signature of the (measured-0-conflict) 16x16 pattern under
// consecutive-16, consecutive-32, and even/odd lane-phasing models; r7's
// pattern (no such term) was 4-way under even/odd phasing -> 1.26e7 confl.
// MFMA 32x32x16 layouts (HW-validated r7): A/B row|col = lane&31,
// k = (lane>>5)*8 + j;  C/D col = lane&31, row = (j&3)+8*(j>>2)+4*(lane>>5).
// =====================================================================
#define BAR() __builtin_amdgcn_s_barrier()
#define LGKM0() do { asm volatile("s_waitcnt lgkmcnt(0)" ::: "memory"); \
                     __builtin_amdgcn_sched_barrier(0); } while (0)
#define STAGE(matv, basev, row0v, tt, hh) do { \
    const h16* _src = (basev) + ((row0v) + (hh) * 128L) * 4096L + (long)(tt) * 64 + scol; \
    h16* _dst = &lds[(((tt) & 1) << 15) + (matv) * 16384 + (hh) * 8192 + w * 512]; \
    gload_lds16(_src, _dst); \
    gload_lds16(_src + 64 * 4096L, _dst + 4096); \
} while (0)
#define LDA32(mh, mf, ks) (*(const h16x8*)&lds[cbuf + (mh) * 8192 + (wm * 64 + (mf) * 32 + l31) * 64 + ((((ks) * 2 + lhi) ^ l7 ^ lb3) << 3)])
#define LDB32(nh, ks)     (*(const h16x8*)&lds[cbuf + 16384 + (nh) * 8192 + (wn * 32 + l31) * 64 + ((((ks) * 2 + lhi) ^ l7 ^ lb3) << 3)])
#define MFMA_Q32(MH, NH, BF) do { \
    __builtin_amdgcn_s_setprio(1); \
    _Pragma("unroll") \
    for (int ks = 0; ks < 4; ++ks) \
        _Pragma("unroll") \
        for (int mf = 0; mf < 2; ++mf) \
            acc[MH][NH][mf] = __builtin_amdgcn_mfma_f32_32x32x16_f16(af[mf][ks], BF[ks], acc[MH][NH][mf], 0, 0, 0); \
    __builtin_amdgcn_s_setprio(0); \
} while (0)

template <typename OUT_T>
__global__ __launch_bounds__(512, 2) void k_gemm256(
    const h16* __restrict__ A, const h16* __restrict__ B,
    OUT_T* __restrict__ C, const float* __restrict__ bias, int nt)
{
    __shared__ __align__(16) h16 lds[65536];   // 128 KiB

    const int tid = threadIdx.x;
    const int w  = tid >> 6, l = tid & 63;
    const int wm = w >> 2, wn = w & 3;          // wave grid 2x4 within each quadrant
    const int l31 = l & 31, lhi = l >> 5, l7 = l & 7, lb3 = (l >> 3) & 1;

    // staging: thread covers 16B; srow in [0,64) per gload, swizzled col
    const int srow = w * 8 + (l >> 3);
    const int scol = (((l & 7) ^ ((l >> 3) & 7) ^ (w & 1)) << 3);
    const long arow0 = (long)blockIdx.x * 256 + srow;
    const long brow0 = (long)blockIdx.y * 256 + srow;

    f32x16 acc[2][2][2] = {};   // [mh][nh][mf]

    // prologue: 0.A0 0.B0 0.A1 0.B1 1.A0 1.B0 (12 loads); vmcnt(4) -> tile0 landed
    STAGE(0, A, arow0, 0, 0);
    STAGE(1, B, brow0, 0, 0);
    STAGE(0, A, arow0, 0, 1);
    STAGE(1, B, brow0, 0, 1);
    STAGE(0, A, arow0, 1, 0);
    STAGE(1, B, brow0, 1, 0);
    asm volatile("s_waitcnt vmcnt(4)" ::: "memory");
    __builtin_amdgcn_sched_barrier(0);
    BAR();

    for (int t = 0; t < nt; ++t) {
        const int cbuf = (t & 1) << 15;
        h16x8 af[2][4], b0[4], b1[4];

        // ---- phase 1: quadrant (0,0) — load A-half0 + B0; stage (t+1).A1 ----
#pragma unroll
        for (int mf = 0; mf < 2; ++mf)
#pragma unroll
            for (int ks = 0; ks < 4; ++ks) af[mf][ks] = LDA32(0, mf, ks);
#pragma unroll
        for (int ks = 0; ks < 4; ++ks) b0[ks] = LDB32(0, ks);
        if (t + 1 < nt) STAGE(0, A, arow0, t + 1, 1);
        BAR(); LGKM0();
        MFMA_Q32(0, 0, b0);
        BAR();

        // ---- phase 2: quadrant (0,1) — load B1; stage (t+1).B1 ----
#pragma unroll
        for (int ks = 0; ks < 4; ++ks) b1[ks] = LDB32(1, ks);
        if (t + 1 < nt) STAGE(1, B, brow0, t + 1, 1);
        BAR(); LGKM0();
        MFMA_Q32(0, 1, b1);
        BAR();

        // ---- phase 3: quadrant (1,0) — load A-half1; stage (t+2).A0 ----
#pragma unroll
        for (int mf = 0; mf < 2; ++mf)
#pragma unroll
            for (int ks = 0; ks < 4; ++ks) af[mf][ks] = LDA32(1, mf, ks);
        if (t + 2 < nt) STAGE(0, A, arow0, t + 2, 0);
        BAR(); LGKM0();
        MFMA_Q32(1, 0, b0);
        BAR();

        // ---- phase 4: quadrant (1,1) — no ds_reads; stage (t+2).B0; drain ----
        if (t + 2 < nt) STAGE(1, B, brow0, t + 2, 0);
        if (t < nt - 2) { asm volatile("s_waitcnt vmcnt(4)" ::: "memory"); }
        else            { asm volatile("s_waitcnt vmcnt(0)" ::: "memory"); }
        __builtin_amdgcn_sched_barrier(0);
        BAR();
        MFMA_Q32(1, 1, b1);
        BAR();
    }

    // epilogue (32x32 C/D layout): row = bx*256 + mh*128 + wm*64 + mf*32
    //   + (j&3) + 8*(j>>2) + 4*lhi ;  col = by*256 + nh*128 + wn*32 + l31
    const long rb  = (long)blockIdx.x * 256 + wm * 64 + 4 * lhi;
    const int  cb0 = (int)blockIdx.y * 256 + wn * 32 + l31;
#pragma unroll
    for (int mh = 0; mh < 2; ++mh)
#pragma unroll
        for (int nh = 0; nh < 2; ++nh) {
            const int col = cb0 + nh * 128;
            const float bv = bias[col];
#pragma unroll
            for (int mf = 0; mf < 2; ++mf) {
                const long r0 = rb + mh * 128 + mf * 32;
#pragma unroll
                for (int j = 0; j < 16; ++j) {
                    const long row = r0 + (j & 3) + 8 * (j >> 2);
                    C[row * 4096L + col] = (OUT_T)(acc[mh][nh][mf][j] + bv);
                }
            }
        }
}

// ---------- GEMM: C[m][n] = alpha * sum_k A[m][k]*B[n][k] (+ bias[n]) ----------
// 128x128 tile, BK=32 (m97 structure) — used for the attention GEMMs.
template <typename OUT_T, bool HAS_BIAS>
__global__ __launch_bounds__(256) void k_gemm_bt(
    const h16* __restrict__ A, const h16* __restrict__ B,
    OUT_T* __restrict__ C, const float* __restrict__ bias,
    int lda, int ldb, int ldc,
    long sAb, long sAh, long sBb, long sBh, long sCb, long sCh,
    float alpha, int kIters)
{
    __shared__ __align__(16) h16 As[128 * 32];
    __shared__ __align__(16) h16 Bs[128 * 32];

    const int z = blockIdx.z, zb = z >> 4, zh = z & 15;
    const h16* Ab = A + zb * sAb + zh * sAh + (long)blockIdx.x * 128 * lda;
    const h16* Bb = B + zb * sBb + zh * sBh + (long)blockIdx.y * 128 * ldb;

    const int tid = threadIdx.x, w = tid >> 6, lane = tid & 63;
    const int wr = (w >> 1) * 64, wc = (w & 1) * 64;
    const int scol = (lane & 3) * 8;
    const int srow = lane >> 2;
    const int koff = (lane >> 4) * 8;
    const int fr   = lane & 15;

    f32x4 acc[4][4] = {};

    for (int kt = 0; kt < kIters; ++kt) {
        const int k0 = kt * 32;
#pragma unroll
        for (int j = 0; j < 2; ++j) {
            const int ca  = w * 2 + j;
            const int row = ca * 16 + srow;
            gload_lds16(Ab + (long)row * lda + k0 + scol, &As[ca * 512]);
            gload_lds16(Bb + (long)row * ldb + k0 + scol, &Bs[ca * 512]);
        }
        __syncthreads();

        h16x8 af[4], bfr[4];
#pragma unroll
        for (int m = 0; m < 4; ++m)
            af[m] = *(const h16x8*)&As[(wr + m * 16 + fr) * 32 + koff];
#pragma unroll
        for (int n = 0; n < 4; ++n)
            bfr[n] = *(const h16x8*)&Bs[(wc + n * 16 + fr) * 32 + koff];
        __syncthreads();

#pragma unroll
        for (int m = 0; m < 4; ++m)
#pragma unroll
            for (int n = 0; n < 4; ++n)
                acc[m][n] = __builtin_amdgcn_mfma_f32_16x16x32_f16(af[m], bfr[n], acc[m][n], 0, 0, 0);
    }

    OUT_T* Cb = C + zb * sCb + zh * sCh;
    const long rbase = (long)blockIdx.x * 128 + wr + (lane >> 4) * 4;
    const int  cbase = blockIdx.y * 128 + wc + fr;
#pragma unroll
    for (int n = 0; n < 4; ++n) {
        const int col = cbase + n * 16;
        const float bv = HAS_BIAS ? bias[col] : 0.0f;
#pragma unroll
        for (int m = 0; m < 4; ++m) {
            const long row0 = rbase + m * 16;
#pragma unroll
            for (int j = 0; j < 4; ++j) {
                float vv = acc[m][n][j] * alpha + bv;
                Cb[(row0 + j) * ldc + col] = (OUT_T)vv;
            }
        }
    }
}

// ---------- transpose V slice: Vt[z][f][t] = Vb[b*1024+t][h*256+f], fp16 ----------
__global__ void k_transpose_v(const h16* __restrict__ Vb, h16* __restrict__ Vt) {
    __shared__ h16 tile[32][34];
    const int z = blockIdx.z, b = z >> 4, h = z & 15;
    const int f0 = blockIdx.x * 32, t0 = blockIdx.y * 32;
    const int tx = threadIdx.x, ty = threadIdx.y;   // 32 x 8
#pragma unroll
    for (int j = 0; j < 4; ++j)
        tile[ty + 8 * j][tx] = Vb[(long)(b * 1024 + t0 + ty + 8 * j) * ED4 + h * 256 + f0 + tx];
    __syncthreads();
#pragma unroll
    for (int j = 0; j < 4; ++j)
        Vt[(long)z * (256 * 1024) + (long)(f0 + ty + 8 * j) * 1024 + t0 + tx] = tile[tx][ty + 8 * j];
}

// ---------- row softmax over S[row][1024] fp16 in place ----------
__global__ __launch_bounds__(256) void k_softmax(h16* __restrict__ S) {
    const long row = blockIdx.x;
    h16* p = S + row * 1024;
    const int tid = threadIdx.x, w = tid >> 6, lane = tid & 63;
    h16x4 xi = *(const h16x4*)&p[tid * 4];
    float x[4];
#pragma unroll
    for (int j = 0; j < 4; ++j) x[j] = (float)xi[j];
    float m = fmaxf(fmaxf(x[0], x[1]), fmaxf(x[2], x[3]));
#pragma unroll
    for (int off = 32; off; off >>= 1) m = fmaxf(m, __shfl_xor(m, off));
    __shared__ float red[8];
    if (lane == 0) red[w] = m;
    __syncthreads();
    m = fmaxf(fmaxf(red[0], red[1]), fmaxf(red[2], red[3]));
    float s = 0.0f;
#pragma unroll
    for (int j = 0; j < 4; ++j) { x[j] = __expf(x[j] - m); s += x[j]; }
#pragma unroll
    for (int off = 32; off; off >>= 1) s += __shfl_xor(s, off);
    if (lane == 0) red[4 + w] = s;
    __syncthreads();
    s = red[4] + red[5] + red[6] + red[7];
    const float inv = 1.0f / s;
    h16x4 o;
#pragma unroll
    for (int j = 0; j < 4; ++j) o[j] = (h16)(x[j] * inv);
    *(h16x4*)&p[tid * 4] = o;
}

// ---------- launch ----------
extern "C" void kernel_launch(void* const* d_in, const int* in_sizes, int n_in,
                              void* d_out, int out_size, void* d_ws, size_t ws_size,
                              hipStream_t stream) {
    const float* q  = (const float*)d_in[0];
    const float* k  = (const float*)d_in[1];
    const float* v  = (const float*)d_in[2];
    const float* Wq = (const float*)d_in[3];
    const float* bq = (const float*)d_in[4];
    const float* Wk = (const float*)d_in[5];
    const float* bk = (const float*)d_in[6];
    const float* Wv = (const float*)d_in[7];
    const float* bv = (const float*)d_in[8];
    const float* Wo = (const float*)d_in[9];
    const float* bo = (const float*)d_in[10];
    float* out = (float*)d_out;

    // workspace layout: 256 MB total (X and M slots are time-shared; scores
    // buffer is chunked per batch, 16 heads x 1024 x 1024 fp16 = 32 MB).
    char* ws = (char*)d_ws;
    const long MB = 1024L * 1024;
    h16* X  = (h16*)(ws + 0 * MB);     // 32 MB: converted q/k/v input (serial)
    h16* M  = (h16*)(ws + 32 * MB);    // 32 MB: effective weight (serial)
    h16* Qb = (h16*)(ws + 64 * MB);
    h16* Kb = (h16*)(ws + 96 * MB);
    h16* Vb = (h16*)(ws + 128 * MB);
    h16* Vt = (h16*)(ws + 160 * MB);
    h16* AO = (h16*)(ws + 192 * MB);
    h16* Sc = (h16*)(ws + 224 * MB);   // 32 MB score chunk (one batch, 16 heads)

    dim3 blk(256);
    dim3 g256(16, 16, 1);

    // Q projection: convert, build weight, GEMM (serially reusing X, M)
    k_f32_to_f16<<<16384, blk, 0, stream>>>(q, X);
    k_build_m<<<16384, blk, 0, stream>>>(Wq, M);
    k_gemm256<h16><<<g256, 512, 0, stream>>>(X, M, Qb, bq, 64);

    // K projection
    k_f32_to_f16<<<16384, blk, 0, stream>>>(k, X);
    k_build_m<<<16384, blk, 0, stream>>>(Wk, M);
    k_gemm256<h16><<<g256, 512, 0, stream>>>(X, M, Kb, bk, 64);

    // V projection
    k_f32_to_f16<<<16384, blk, 0, stream>>>(v, X);
    k_build_m<<<16384, blk, 0, stream>>>(Wv, M);
    k_gemm256<h16><<<g256, 512, 0, stream>>>(X, M, Vb, bv, 64);

    // V transpose per (b,h): Vt[z][256][1024]
    k_transpose_v<<<dim3(8, 32, 64), dim3(32, 8), 0, stream>>>(Vb, Vt);

    // attention, one batch (16 heads) at a time through the 32 MB score chunk
    for (int c = 0; c < 4; ++c) {
        const h16* Qc  = Qb + (long)c * 1024 * 4096;
        const h16* Kc  = Kb + (long)c * 1024 * 4096;
        const h16* VtC = Vt + (long)c * 16 * 256 * 1024;
        h16*       AOc = AO + (long)c * 1024 * 4096;

        // scores: Sc[zh][1024][1024] = (Q K^T)/16, fp16
        k_gemm_bt<h16, false><<<dim3(8, 8, 16), blk, 0, stream>>>(
            Qc, Kc, Sc, nullptr,
            4096, 4096, 1024,
            0, 256,                       // A: h-stride (256-col slices)
            0, 256,                       // B
            0, 1024L * 1024,              // C
            0.0625f, 8);

        // softmax rows in place (fp16)
        k_softmax<<<16384, blk, 0, stream>>>(Sc);

        // attn out: AOc[t][h*256+f] = P_zh . Vt_zh^T
        k_gemm_bt<h16, false><<<dim3(8, 2, 16), blk, 0, stream>>>(
            Sc, VtC, AOc, nullptr,
            1024, 1024, 4096,
            0, 1024L * 1024,              // A
            0, 256L * 1024,               // B
            0, 256,                       // C
            1.0f, 32);
    }

    // output projection: out = AO . Mo^T + bo (fp32 out)
    k_build_m<<<16384, blk, 0, stream>>>(Wo, M);
    k_gemm256<float><<<g256, 512, 0, stream>>>(AO, M, out, bo, 64);
}

// Round 9
// 906.742 us; speedup vs baseline: 1.0803x; 1.0615x over previous
//
#include <hip/hip_runtime.h>
#include <hip/hip_bf16.h>

// ---------- types ----------
typedef _Float16 h16;
typedef h16   h16x8 __attribute__((ext_vector_type(8)));
typedef h16   h16x4 __attribute__((ext_vector_type(4)));
typedef float f32x4 __attribute__((ext_vector_type(4)));

#define EMB 1024
#define ED4 4096L   // EMB*4 flattened feature dim

// ---------- async global->LDS (16B per lane, wave-uniform LDS base) ----------
__device__ __forceinline__ void gload_lds16(const void* g, void* l) {
    __builtin_amdgcn_global_load_lds(
        (__attribute__((address_space(1))) void*)g,
        (__attribute__((address_space(3))) void*)l,
        16, 0, 0);
}

// ---------- build effective block weight M[o*4+q][i*4+c] = s(q,c)*W[q^c][o][i], fp16 ----------
__global__ __launch_bounds__(256) void k_build_m(const float* __restrict__ W, h16* __restrict__ M) {
    int t = blockIdx.x * 256 + threadIdx.x;   // [0, 4096*1024)
    int i = t & 1023;
    int n = t >> 10;          // o*4+q
    int o = n >> 2, q = n & 3;
    // sign masks per q (bit c set => negative): q0:0xE q1:0x8 q2:0x2 q3:0x4
    unsigned packed = 0xEu | (0x8u << 4) | (0x2u << 8) | (0x4u << 12);
    unsigned sm = (packed >> (q * 4)) & 0xFu;
    h16x4 out;
#pragma unroll
    for (int c = 0; c < 4; ++c) {
        int d = q ^ c;
        float w = W[((long)d * EMB + o) * EMB + i];
        out[c] = (h16)(((sm >> c) & 1u) ? -w : w);
    }
    *(h16x4*)&M[(long)n * ED4 + i * 4] = out;
}

// ---------- fp32 -> fp16 convert (x inputs), 4 elems/thread ----------
__global__ __launch_bounds__(256) void k_f32_to_f16(const float* __restrict__ in, h16* __restrict__ out) {
    long i = ((long)blockIdx.x * 256 + threadIdx.x) * 4;
    float4 v = *(const float4*)(in + i);
    h16x4 o;
    o[0] = (h16)v.x; o[1] = (h16)v.y; o[2] = (h16)v.z; o[3] = (h16)v.w;
    *(h16x4*)(out + i) = o;
}

// =====================================================================
// 256x256-tile, BK=64, 4-phase fine-interleaved GEMM (4096x4096x4096)
// EXACT round-6 kernel (best measured: 139us, MfmaUtil 42.5%, 0 bank
// conflicts). 16x16x32 MFMA; ledger and counted-vmcnt as documented.
// =====================================================================
#define BAR() __builtin_amdgcn_s_barrier()
#define LGKM0() do { asm volatile("s_waitcnt lgkmcnt(0)" ::: "memory"); \
                     __builtin_amdgcn_sched_barrier(0); } while (0)
#define STAGE(matv, basev, row0v, tt, hh) do { \
    const h16* _src = (basev) + ((row0v) + (hh) * 128L) * 4096L + (long)(tt) * 64 + scol; \
    h16* _dst = &lds[(((tt) & 1) << 15) + (matv) * 16384 + (hh) * 8192 + w * 512]; \
    gload_lds16(_src, _dst); \
    gload_lds16(_src + 64 * 4096L, _dst + 4096); \
} while (0)
#define LDA_(mh, m, ks) (*(const h16x8*)&lds[cb + (mh) * 8192 + (wm * 64 + (m) * 16 + fr) * 64 + ((((ks) * 4 + kq) ^ fr7) << 3)])
#define LDB_(nh, n, ks) (*(const h16x8*)&lds[cb + 16384 + (nh) * 8192 + (wn * 32 + (n) * 16 + fr) * 64 + ((((ks) * 4 + kq) ^ fr7) << 3)])
#define MFMA_Q(MH, NH, BF) do { \
    __builtin_amdgcn_s_setprio(1); \
    _Pragma("unroll") \
    for (int m = 0; m < 4; ++m) \
        _Pragma("unroll") \
        for (int n = 0; n < 2; ++n) { \
            acc[MH][NH][m][n] = __builtin_amdgcn_mfma_f32_16x16x32_f16(af[m][0], BF[n][0], acc[MH][NH][m][n], 0, 0, 0); \
            acc[MH][NH][m][n] = __builtin_amdgcn_mfma_f32_16x16x32_f16(af[m][1], BF[n][1], acc[MH][NH][m][n], 0, 0, 0); \
        } \
    __builtin_amdgcn_s_setprio(0); \
} while (0)

template <typename OUT_T>
__global__ __launch_bounds__(512, 2) void k_gemm256(
    const h16* __restrict__ A, const h16* __restrict__ B,
    OUT_T* __restrict__ C, const float* __restrict__ bias, int nt)
{
    __shared__ __align__(16) h16 lds[65536];   // 128 KiB

    const int tid = threadIdx.x;
    const int w  = tid >> 6, l = tid & 63;
    const int wm = w >> 2, wn = w & 3;          // wave grid 2x4 within each quadrant
    const int fr = l & 15, fr7 = l & 7, kq = l >> 4;

    // staging: thread covers 16B; srow in [0,64) per gload, swizzled col
    const int srow = w * 8 + (l >> 3);
    const int scol = ((l & 7) ^ ((l >> 3) & 7)) << 3;
    const long arow0 = (long)blockIdx.x * 256 + srow;
    const long brow0 = (long)blockIdx.y * 256 + srow;

    f32x4 acc[2][2][4][2] = {};   // [mh][nh][m][n]

    // prologue: 0.A0 0.B0 0.A1 0.B1 1.A0 1.B0 (12 loads); vmcnt(4) -> tile0 landed
    STAGE(0, A, arow0, 0, 0);
    STAGE(1, B, brow0, 0, 0);
    STAGE(0, A, arow0, 0, 1);
    STAGE(1, B, brow0, 0, 1);
    STAGE(0, A, arow0, 1, 0);
    STAGE(1, B, brow0, 1, 0);
    asm volatile("s_waitcnt vmcnt(4)" ::: "memory");
    __builtin_amdgcn_sched_barrier(0);
    BAR();

    for (int t = 0; t < nt; ++t) {
        const int cb = (t & 1) << 15;
        h16x8 af[4][2], b0[2][2], b1[2][2];

        // ---- phase 1: quadrant (0,0) — load A0 + B0; stage (t+1).A1 ----
#pragma unroll
        for (int m = 0; m < 4; ++m) { af[m][0] = LDA_(0, m, 0); af[m][1] = LDA_(0, m, 1); }
#pragma unroll
        for (int n = 0; n < 2; ++n) { b0[n][0] = LDB_(0, n, 0); b0[n][1] = LDB_(0, n, 1); }
        if (t + 1 < nt) STAGE(0, A, arow0, t + 1, 1);
        BAR(); LGKM0();
        MFMA_Q(0, 0, b0);
        BAR();

        // ---- phase 2: quadrant (0,1) — load B1; stage (t+1).B1 ----
#pragma unroll
        for (int n = 0; n < 2; ++n) { b1[n][0] = LDB_(1, n, 0); b1[n][1] = LDB_(1, n, 1); }
        if (t + 1 < nt) STAGE(1, B, brow0, t + 1, 1);
        BAR(); LGKM0();
        MFMA_Q(0, 1, b1);
        BAR();

        // ---- phase 3: quadrant (1,0) — load A1; stage (t+2).A0 ----
#pragma unroll
        for (int m = 0; m < 4; ++m) { af[m][0] = LDA_(1, m, 0); af[m][1] = LDA_(1, m, 1); }
        if (t + 2 < nt) STAGE(0, A, arow0, t + 2, 0);
        BAR(); LGKM0();
        MFMA_Q(1, 0, b0);
        BAR();

        // ---- phase 4: quadrant (1,1) — no ds_reads; stage (t+2).B0; drain ----
        if (t + 2 < nt) STAGE(1, B, brow0, t + 2, 0);
        if (t < nt - 2) { asm volatile("s_waitcnt vmcnt(4)" ::: "memory"); }
        else            { asm volatile("s_waitcnt vmcnt(0)" ::: "memory"); }
        __builtin_amdgcn_sched_barrier(0);
        BAR();
        MFMA_Q(1, 1, b1);
        BAR();
    }

    // epilogue: row = bx*256 + mh*128 + wm*64 + m*16 + kq*4 + j
    //           col = by*256 + nh*128 + wn*32 + n*16 + fr
    const long row00 = (long)blockIdx.x * 256 + wm * 64 + kq * 4;
    const int  col00 = (int)blockIdx.y * 256 + wn * 32 + fr;
#pragma unroll
    for (int mh = 0; mh < 2; ++mh)
#pragma unroll
        for (int nh = 0; nh < 2; ++nh)
#pragma unroll
            for (int n = 0; n < 2; ++n) {
                const int col = col00 + nh * 128 + n * 16;
                const float bv = bias[col];
#pragma unroll
                for (int m = 0; m < 4; ++m) {
                    const long r0 = row00 + mh * 128 + m * 16;
#pragma unroll
                    for (int j = 0; j < 4; ++j)
                        C[(r0 + j) * 4096L + col] = (OUT_T)(acc[mh][nh][m][n][j] + bv);
                }
            }
}

// ---------- GEMM: C[m][n] = alpha * sum_k A[m][k]*B[n][k] (+ bias[n]) ----------
// 128x128 tile, BK=32 (m97 structure) — used for the attention GEMMs.
// r9: LDS XOR-swizzle added (T2). R3 profile showed 1.68e7 bank conflicts:
// old read koff=(lane>>4)*8 put lanes 0-15 on 2 bank-quads (8-way).
// Involution: LDS row r holds global 16B-slot s at LDS slot s ^ ((r>>1)&3).
//   store (linear LDS dest, pre-swizzled global src): lane writes LDS slot
//     lane&3 at row lane>>2 -> src slot = (lane&3) ^ ((lane>>3)&3)
//   read: fragment row fr, k-quad kq -> LDS slot kq ^ ((fr>>1)&3)
// Lanes fr=0..7 now hit bank-quads {0,4,1,5,2,6,3,7} (2 lanes/quad = free).
template <typename OUT_T, bool HAS_BIAS>
__global__ __launch_bounds__(256) void k_gemm_bt(
    const h16* __restrict__ A, const h16* __restrict__ B,
    OUT_T* __restrict__ C, const float* __restrict__ bias,
    int lda, int ldb, int ldc,
    long sAb, long sAh, long sBb, long sBh, long sCb, long sCh,
    float alpha, int kIters)
{
    __shared__ __align__(16) h16 As[128 * 32];
    __shared__ __align__(16) h16 Bs[128 * 32];

    const int z = blockIdx.z, zb = z >> 4, zh = z & 15;
    const h16* Ab = A + zb * sAb + zh * sAh + (long)blockIdx.x * 128 * lda;
    const h16* Bb = B + zb * sBb + zh * sBh + (long)blockIdx.y * 128 * ldb;

    const int tid = threadIdx.x, w = tid >> 6, lane = tid & 63;
    const int wr = (w >> 1) * 64, wc = (w & 1) * 64;
    const int scol = (((lane & 3) ^ ((lane >> 3) & 3)) * 8);   // swizzled global src slot
    const int srow = lane >> 2;
    const int fr   = lane & 15;
    const int koff = (((lane >> 4) ^ ((fr >> 1) & 3)) * 8);    // swizzled LDS read slot

    f32x4 acc[4][4] = {};

    for (int kt = 0; kt < kIters; ++kt) {
        const int k0 = kt * 32;
#pragma unroll
        for (int j = 0; j < 2; ++j) {
            const int ca  = w * 2 + j;
            const int row = ca * 16 + srow;
            gload_lds16(Ab + (long)row * lda + k0 + scol, &As[ca * 512]);
            gload_lds16(Bb + (long)row * ldb + k0 + scol, &Bs[ca * 512]);
        }
        __syncthreads();

        h16x8 af[4], bfr[4];
#pragma unroll
        for (int m = 0; m < 4; ++m)
            af[m] = *(const h16x8*)&As[(wr + m * 16 + fr) * 32 + koff];
#pragma unroll
        for (int n = 0; n < 4; ++n)
            bfr[n] = *(const h16x8*)&Bs[(wc + n * 16 + fr) * 32 + koff];
        __syncthreads();

#pragma unroll
        for (int m = 0; m < 4; ++m)
#pragma unroll
            for (int n = 0; n < 4; ++n)
                acc[m][n] = __builtin_amdgcn_mfma_f32_16x16x32_f16(af[m], bfr[n], acc[m][n], 0, 0, 0);
    }

    OUT_T* Cb = C + zb * sCb + zh * sCh;
    const long rbase = (long)blockIdx.x * 128 + wr + (lane >> 4) * 4;
    const int  cbase = blockIdx.y * 128 + wc + fr;
#pragma unroll
    for (int n = 0; n < 4; ++n) {
        const int col = cbase + n * 16;
        const float bv = HAS_BIAS ? bias[col] : 0.0f;
#pragma unroll
        for (int m = 0; m < 4; ++m) {
            const long row0 = rbase + m * 16;
#pragma unroll
            for (int j = 0; j < 4; ++j) {
                float vv = acc[m][n][j] * alpha + bv;
                Cb[(row0 + j) * ldc + col] = (OUT_T)vv;
            }
        }
    }
}

// ---------- transpose V slice: Vt[z][f][t] = Vb[b*1024+t][h*256+f], fp16 ----------
__global__ void k_transpose_v(const h16* __restrict__ Vb, h16* __restrict__ Vt) {
    __shared__ h16 tile[32][34];
    const int z = blockIdx.z, b = z >> 4, h = z & 15;
    const int f0 = blockIdx.x * 32, t0 = blockIdx.y * 32;
    const int tx = threadIdx.x, ty = threadIdx.y;   // 32 x 8
#pragma unroll
    for (int j = 0; j < 4; ++j)
        tile[ty + 8 * j][tx] = Vb[(long)(b * 1024 + t0 + ty + 8 * j) * ED4 + h * 256 + f0 + tx];
    __syncthreads();
#pragma unroll
    for (int j = 0; j < 4; ++j)
        Vt[(long)z * (256 * 1024) + (long)(f0 + ty + 8 * j) * 1024 + t0 + tx] = tile[tx][ty + 8 * j];
}

// ---------- row softmax over S[row][1024] fp16 in place ----------
__global__ __launch_bounds__(256) void k_softmax(h16* __restrict__ S) {
    const long row = blockIdx.x;
    h16* p = S + row * 1024;
    const int tid = threadIdx.x, w = tid >> 6, lane = tid & 63;
    h16x4 xi = *(const h16x4*)&p[tid * 4];
    float x[4];
#pragma unroll
    for (int j = 0; j < 4; ++j) x[j] = (float)xi[j];
    float m = fmaxf(fmaxf(x[0], x[1]), fmaxf(x[2], x[3]));
#pragma unroll
    for (int off = 32; off; off >>= 1) m = fmaxf(m, __shfl_xor(m, off));
    __shared__ float red[8];
    if (lane == 0) red[w] = m;
    __syncthreads();
    m = fmaxf(fmaxf(red[0], red[1]), fmaxf(red[2], red[3]));
    float s = 0.0f;
#pragma unroll
    for (int j = 0; j < 4; ++j) { x[j] = __expf(x[j] - m); s += x[j]; }
#pragma unroll
    for (int off = 32; off; off >>= 1) s += __shfl_xor(s, off);
    if (lane == 0) red[4 + w] = s;
    __syncthreads();
    s = red[4] + red[5] + red[6] + red[7];
    const float inv = 1.0f / s;
    h16x4 o;
#pragma unroll
    for (int j = 0; j < 4; ++j) o[j] = (h16)(x[j] * inv);
    *(h16x4*)&p[tid * 4] = o;
}

// ---------- launch ----------
extern "C" void kernel_launch(void* const* d_in, const int* in_sizes, int n_in,
                              void* d_out, int out_size, void* d_ws, size_t ws_size,
                              hipStream_t stream) {
    const float* q  = (const float*)d_in[0];
    const float* k  = (const float*)d_in[1];
    const float* v  = (const float*)d_in[2];
    const float* Wq = (const float*)d_in[3];
    const float* bq = (const float*)d_in[4];
    const float* Wk = (const float*)d_in[5];
    const float* bk = (const float*)d_in[6];
    const float* Wv = (const float*)d_in[7];
    const float* bv = (const float*)d_in[8];
    const float* Wo = (const float*)d_in[9];
    const float* bo = (const float*)d_in[10];
    float* out = (float*)d_out;

    // workspace layout: 256 MB total (X and M slots are time-shared; scores
    // buffer is chunked per batch, 16 heads x 1024 x 1024 fp16 = 32 MB).
    char* ws = (char*)d_ws;
    const long MB = 1024L * 1024;
    h16* X  = (h16*)(ws + 0 * MB);     // 32 MB: converted q/k/v input (serial)
    h16* M  = (h16*)(ws + 32 * MB);    // 32 MB: effective weight (serial)
    h16* Qb = (h16*)(ws + 64 * MB);
    h16* Kb = (h16*)(ws + 96 * MB);
    h16* Vb = (h16*)(ws + 128 * MB);
    h16* Vt = (h16*)(ws + 160 * MB);
    h16* AO = (h16*)(ws + 192 * MB);
    h16* Sc = (h16*)(ws + 224 * MB);   // 32 MB score chunk (one batch, 16 heads)

    dim3 blk(256);
    dim3 g256(16, 16, 1);

    // Q projection: convert, build weight, GEMM (serially reusing X, M)
    k_f32_to_f16<<<16384, blk, 0, stream>>>(q, X);
    k_build_m<<<16384, blk, 0, stream>>>(Wq, M);
    k_gemm256<h16><<<g256, 512, 0, stream>>>(X, M, Qb, bq, 64);

    // K projection
    k_f32_to_f16<<<16384, blk, 0, stream>>>(k, X);
    k_build_m<<<16384, blk, 0, stream>>>(Wk, M);
    k_gemm256<h16><<<g256, 512, 0, stream>>>(X, M, Kb, bk, 64);

    // V projection
    k_f32_to_f16<<<16384, blk, 0, stream>>>(v, X);
    k_build_m<<<16384, blk, 0, stream>>>(Wv, M);
    k_gemm256<h16><<<g256, 512, 0, stream>>>(X, M, Vb, bv, 64);

    // V transpose per (b,h): Vt[z][256][1024]
    k_transpose_v<<<dim3(8, 32, 64), dim3(32, 8), 0, stream>>>(Vb, Vt);

    // attention, one batch (16 heads) at a time through the 32 MB score chunk
    for (int c = 0; c < 4; ++c) {
        const h16* Qc  = Qb + (long)c * 1024 * 4096;
        const h16* Kc  = Kb + (long)c * 1024 * 4096;
        const h16* VtC = Vt + (long)c * 16 * 256 * 1024;
        h16*       AOc = AO + (long)c * 1024 * 4096;

        // scores: Sc[zh][1024][1024] = (Q K^T)/16, fp16
        k_gemm_bt<h16, false><<<dim3(8, 8, 16), blk, 0, stream>>>(
            Qc, Kc, Sc, nullptr,
            4096, 4096, 1024,
            0, 256,                       // A: h-stride (256-col slices)
            0, 256,                       // B
            0, 1024L * 1024,              // C
            0.0625f, 8);

        // softmax rows in place (fp16)
        k_softmax<<<16384, blk, 0, stream>>>(Sc);

        // attn out: AOc[t][h*256+f] = P_zh . Vt_zh^T
        k_gemm_bt<h16, false><<<dim3(8, 2, 16), blk, 0, stream>>>(
            Sc, VtC, AOc, nullptr,
            1024, 1024, 4096,
            0, 1024L * 1024,              // A
            0, 256L * 1024,               // B
            0, 256,                       // C
            1.0f, 32);
    }

    // output projection: out = AO . Mo^T + bo (fp32 out)
    k_build_m<<<16384, blk, 0, stream>>>(Wo, M);
    k_gemm256<float><<<g256, 512, 0, stream>>>(AO, M, out, bo, 64);
}

// Round 10
// 874.377 us; speedup vs baseline: 1.1203x; 1.0370x over previous
//
#include <hip/hip_runtime.h>
#include <hip/hip_bf16.h>

// ---------- types ----------
typedef _Float16 h16;
typedef h16   h16x8 __attribute__((ext_vector_type(8)));
typedef h16   h16x4 __attribute__((ext_vector_type(4)));
typedef float f32x4 __attribute__((ext_vector_type(4)));

#define EMB 1024
#define ED4 4096L   // EMB*4 flattened feature dim

// ---------- async global->LDS (16B per lane, wave-uniform LDS base) ----------
__device__ __forceinline__ void gload_lds16(const void* g, void* l) {
    __builtin_amdgcn_global_load_lds(
        (__attribute__((address_space(1))) void*)g,
        (__attribute__((address_space(3))) void*)l,
        16, 0, 0);
}

// ---------- build effective block weight M[o*4+q][i*4+c] = s(q,c)*W[q^c][o][i], fp16 ----------
__global__ __launch_bounds__(256) void k_build_m(const float* __restrict__ W, h16* __restrict__ M) {
    int t = blockIdx.x * 256 + threadIdx.x;   // [0, 4096*1024)
    int i = t & 1023;
    int n = t >> 10;          // o*4+q
    int o = n >> 2, q = n & 3;
    // sign masks per q (bit c set => negative): q0:0xE q1:0x8 q2:0x2 q3:0x4
    unsigned packed = 0xEu | (0x8u << 4) | (0x2u << 8) | (0x4u << 12);
    unsigned sm = (packed >> (q * 4)) & 0xFu;
    h16x4 out;
#pragma unroll
    for (int c = 0; c < 4; ++c) {
        int d = q ^ c;
        float w = W[((long)d * EMB + o) * EMB + i];
        out[c] = (h16)(((sm >> c) & 1u) ? -w : w);
    }
    *(h16x4*)&M[(long)n * ED4 + i * 4] = out;
}

// ---------- fp32 -> fp16 convert (x inputs), 4 elems/thread ----------
__global__ __launch_bounds__(256) void k_f32_to_f16(const float* __restrict__ in, h16* __restrict__ out) {
    long i = ((long)blockIdx.x * 256 + threadIdx.x) * 4;
    float4 v = *(const float4*)(in + i);
    h16x4 o;
    o[0] = (h16)v.x; o[1] = (h16)v.y; o[2] = (h16)v.z; o[3] = (h16)v.w;
    *(h16x4*)(out + i) = o;
}

// =====================================================================
// 256x256-tile, BK=64, 4-phase fine-interleaved GEMM (4096x4096x4096)
// r10 change vs round-6/9 green kernel: pre-MFMA barrier DELETED (one
// barrier per phase, post-MFMA only). Correctness ledger: each wave
// drains its own ds_reads via lgkmcnt(0) BEFORE its MFMA, hence before
// reaching the post-MFMA barrier; therefore once any wave passes that
// barrier, all reads chip-wide are complete. Every STAGE targets a
// region whose last reader drained >=1 post-barrier earlier:
//   (t+1).A1 staged ph1(t): prev contents (t-1).A1 last read ph3(t-1)
//   (t+1).B1 staged ph2(t): prev (t-1).B1 last read ph2(t-1)
//   (t+2).A0 staged ph3(t): prev (t).A0   last read ph1(t)
//   (t+2).B0 staged ph4(t): prev (t).B0   last read ph1(t)
// Landing: vmcnt(4)@ph4(t) leaves newest 4 loads (ph3/ph4 stages of t+2)
// in flight; everything tile t+1 reads has landed. vmcnt(0) at t>=nt-2.
// Benefit: waves slip within a phase -> LDS reads of slow waves overlap
// MFMA of fast waves (m114 mechanism); setprio(1) arbitration now acts.
// VT=true variant (V projection): epilogue writes the per-(b,h)
// transposed layout Vt[(b*16+h)][f][t] directly as contiguous h16x4
// (j-loop spans consecutive t), replacing the separate transpose kernel.
// =====================================================================
#define BAR() __builtin_amdgcn_s_barrier()
#define LGKM0() do { asm volatile("s_waitcnt lgkmcnt(0)" ::: "memory"); \
                     __builtin_amdgcn_sched_barrier(0); } while (0)
#define STAGE(matv, basev, row0v, tt, hh) do { \
    const h16* _src = (basev) + ((row0v) + (hh) * 128L) * 4096L + (long)(tt) * 64 + scol; \
    h16* _dst = &lds[(((tt) & 1) << 15) + (matv) * 16384 + (hh) * 8192 + w * 512]; \
    gload_lds16(_src, _dst); \
    gload_lds16(_src + 64 * 4096L, _dst + 4096); \
} while (0)
#define LDA_(mh, m, ks) (*(const h16x8*)&lds[cb + (mh) * 8192 + (wm * 64 + (m) * 16 + fr) * 64 + ((((ks) * 4 + kq) ^ fr7) << 3)])
#define LDB_(nh, n, ks) (*(const h16x8*)&lds[cb + 16384 + (nh) * 8192 + (wn * 32 + (n) * 16 + fr) * 64 + ((((ks) * 4 + kq) ^ fr7) << 3)])
#define MFMA_Q(MH, NH, BF) do { \
    __builtin_amdgcn_s_setprio(1); \
    _Pragma("unroll") \
    for (int m = 0; m < 4; ++m) \
        _Pragma("unroll") \
        for (int n = 0; n < 2; ++n) { \
            acc[MH][NH][m][n] = __builtin_amdgcn_mfma_f32_16x16x32_f16(af[m][0], BF[n][0], acc[MH][NH][m][n], 0, 0, 0); \
            acc[MH][NH][m][n] = __builtin_amdgcn_mfma_f32_16x16x32_f16(af[m][1], BF[n][1], acc[MH][NH][m][n], 0, 0, 0); \
        } \
    __builtin_amdgcn_s_setprio(0); \
} while (0)

template <typename OUT_T, bool VT>
__global__ __launch_bounds__(512, 2) void k_gemm256(
    const h16* __restrict__ A, const h16* __restrict__ B,
    OUT_T* __restrict__ C, const float* __restrict__ bias, int nt)
{
    __shared__ __align__(16) h16 lds[65536];   // 128 KiB

    const int tid = threadIdx.x;
    const int w  = tid >> 6, l = tid & 63;
    const int wm = w >> 2, wn = w & 3;          // wave grid 2x4 within each quadrant
    const int fr = l & 15, fr7 = l & 7, kq = l >> 4;

    // staging: thread covers 16B; srow in [0,64) per gload, swizzled col
    const int srow = w * 8 + (l >> 3);
    const int scol = ((l & 7) ^ ((l >> 3) & 7)) << 3;
    const long arow0 = (long)blockIdx.x * 256 + srow;
    const long brow0 = (long)blockIdx.y * 256 + srow;

    f32x4 acc[2][2][4][2] = {};   // [mh][nh][m][n]

    // prologue: 0.A0 0.B0 0.A1 0.B1 1.A0 1.B0 (12 loads); vmcnt(4) -> tile0 landed
    STAGE(0, A, arow0, 0, 0);
    STAGE(1, B, brow0, 0, 0);
    STAGE(0, A, arow0, 0, 1);
    STAGE(1, B, brow0, 0, 1);
    STAGE(0, A, arow0, 1, 0);
    STAGE(1, B, brow0, 1, 0);
    asm volatile("s_waitcnt vmcnt(4)" ::: "memory");
    __builtin_amdgcn_sched_barrier(0);
    BAR();

    for (int t = 0; t < nt; ++t) {
        const int cb = (t & 1) << 15;
        h16x8 af[4][2], b0[2][2], b1[2][2];

        // ---- phase 1: quadrant (0,0) — load A0 + B0; stage (t+1).A1 ----
#pragma unroll
        for (int m = 0; m < 4; ++m) { af[m][0] = LDA_(0, m, 0); af[m][1] = LDA_(0, m, 1); }
#pragma unroll
        for (int n = 0; n < 2; ++n) { b0[n][0] = LDB_(0, n, 0); b0[n][1] = LDB_(0, n, 1); }
        if (t + 1 < nt) STAGE(0, A, arow0, t + 1, 1);
        LGKM0();
        MFMA_Q(0, 0, b0);
        BAR();

        // ---- phase 2: quadrant (0,1) — load B1; stage (t+1).B1 ----
#pragma unroll
        for (int n = 0; n < 2; ++n) { b1[n][0] = LDB_(1, n, 0); b1[n][1] = LDB_(1, n, 1); }
        if (t + 1 < nt) STAGE(1, B, brow0, t + 1, 1);
        LGKM0();
        MFMA_Q(0, 1, b1);
        BAR();

        // ---- phase 3: quadrant (1,0) — load A1; stage (t+2).A0 ----
#pragma unroll
        for (int m = 0; m < 4; ++m) { af[m][0] = LDA_(1, m, 0); af[m][1] = LDA_(1, m, 1); }
        if (t + 2 < nt) STAGE(0, A, arow0, t + 2, 0);
        LGKM0();
        MFMA_Q(1, 0, b0);
        BAR();

        // ---- phase 4: quadrant (1,1) — no ds_reads; stage (t+2).B0; drain ----
        if (t + 2 < nt) STAGE(1, B, brow0, t + 2, 0);
        if (t < nt - 2) { asm volatile("s_waitcnt vmcnt(4)" ::: "memory"); }
        else            { asm volatile("s_waitcnt vmcnt(0)" ::: "memory"); }
        __builtin_amdgcn_sched_barrier(0);
        MFMA_Q(1, 1, b1);
        BAR();
    }

    // epilogue: row = bx*256 + mh*128 + wm*64 + m*16 + kq*4 + j
    //           col = by*256 + nh*128 + wn*32 + n*16 + fr
    const long row00 = (long)blockIdx.x * 256 + wm * 64 + kq * 4;
    const int  col00 = (int)blockIdx.y * 256 + wn * 32 + fr;
#pragma unroll
    for (int mh = 0; mh < 2; ++mh)
#pragma unroll
        for (int nh = 0; nh < 2; ++nh)
#pragma unroll
            for (int n = 0; n < 2; ++n) {
                const int col = col00 + nh * 128 + n * 16;
                const float bv = bias[col];
#pragma unroll
                for (int m = 0; m < 4; ++m) {
                    const long r0 = row00 + mh * 128 + m * 16;
                    if constexpr (VT) {
                        // Vt[(r>>10)*16 + (col>>8)][col&255][r&1023], r0 % 4 == 0
                        h16x4 o;
#pragma unroll
                        for (int j = 0; j < 4; ++j) o[j] = (h16)(acc[mh][nh][m][n][j] + bv);
                        const long zidx = (r0 >> 10) * 16 + (col >> 8);
                        *(h16x4*)((h16*)C + zidx * 262144L + (long)(col & 255) * 1024 + (r0 & 1023)) = o;
                    } else {
#pragma unroll
                        for (int j = 0; j < 4; ++j)
                            C[(r0 + j) * 4096L + col] = (OUT_T)(acc[mh][nh][m][n][j] + bv);
                    }
                }
            }
}

// ---------- GEMM: C[m][n] = alpha * sum_k A[m][k]*B[n][k] (+ bias[n]) ----------
// 128x128 tile, BK=32 (m97 structure) — used for the attention GEMMs.
// LDS XOR-swizzle (r9): LDS row r holds global 16B-slot s at slot s ^ ((r>>1)&3).
template <typename OUT_T, bool HAS_BIAS>
__global__ __launch_bounds__(256) void k_gemm_bt(
    const h16* __restrict__ A, const h16* __restrict__ B,
    OUT_T* __restrict__ C, const float* __restrict__ bias,
    int lda, int ldb, int ldc,
    long sAb, long sAh, long sBb, long sBh, long sCb, long sCh,
    float alpha, int kIters)
{
    __shared__ __align__(16) h16 As[128 * 32];
    __shared__ __align__(16) h16 Bs[128 * 32];

    const int z = blockIdx.z, zb = z >> 4, zh = z & 15;
    const h16* Ab = A + zb * sAb + zh * sAh + (long)blockIdx.x * 128 * lda;
    const h16* Bb = B + zb * sBb + zh * sBh + (long)blockIdx.y * 128 * ldb;

    const int tid = threadIdx.x, w = tid >> 6, lane = tid & 63;
    const int wr = (w >> 1) * 64, wc = (w & 1) * 64;
    const int scol = (((lane & 3) ^ ((lane >> 3) & 3)) * 8);   // swizzled global src slot
    const int srow = lane >> 2;
    const int fr   = lane & 15;
    const int koff = (((lane >> 4) ^ ((fr >> 1) & 3)) * 8);    // swizzled LDS read slot

    f32x4 acc[4][4] = {};

    for (int kt = 0; kt < kIters; ++kt) {
        const int k0 = kt * 32;
#pragma unroll
        for (int j = 0; j < 2; ++j) {
            const int ca  = w * 2 + j;
            const int row = ca * 16 + srow;
            gload_lds16(Ab + (long)row * lda + k0 + scol, &As[ca * 512]);
            gload_lds16(Bb + (long)row * ldb + k0 + scol, &Bs[ca * 512]);
        }
        __syncthreads();

        h16x8 af[4], bfr[4];
#pragma unroll
        for (int m = 0; m < 4; ++m)
            af[m] = *(const h16x8*)&As[(wr + m * 16 + fr) * 32 + koff];
#pragma unroll
        for (int n = 0; n < 4; ++n)
            bfr[n] = *(const h16x8*)&Bs[(wc + n * 16 + fr) * 32 + koff];
        __syncthreads();

#pragma unroll
        for (int m = 0; m < 4; ++m)
#pragma unroll
            for (int n = 0; n < 4; ++n)
                acc[m][n] = __builtin_amdgcn_mfma_f32_16x16x32_f16(af[m], bfr[n], acc[m][n], 0, 0, 0);
    }

    OUT_T* Cb = C + zb * sCb + zh * sCh;
    const long rbase = (long)blockIdx.x * 128 + wr + (lane >> 4) * 4;
    const int  cbase = blockIdx.y * 128 + wc + fr;
#pragma unroll
    for (int n = 0; n < 4; ++n) {
        const int col = cbase + n * 16;
        const float bv = HAS_BIAS ? bias[col] : 0.0f;
#pragma unroll
        for (int m = 0; m < 4; ++m) {
            const long row0 = rbase + m * 16;
#pragma unroll
            for (int j = 0; j < 4; ++j) {
                float vv = acc[m][n][j] * alpha + bv;
                Cb[(row0 + j) * ldc + col] = (OUT_T)vv;
            }
        }
    }
}

// ---------- row softmax over S[row][1024] fp16 in place ----------
__global__ __launch_bounds__(256) void k_softmax(h16* __restrict__ S) {
    const long row = blockIdx.x;
    h16* p = S + row * 1024;
    const int tid = threadIdx.x, w = tid >> 6, lane = tid & 63;
    h16x4 xi = *(const h16x4*)&p[tid * 4];
    float x[4];
#pragma unroll
    for (int j = 0; j < 4; ++j) x[j] = (float)xi[j];
    float m = fmaxf(fmaxf(x[0], x[1]), fmaxf(x[2], x[3]));
#pragma unroll
    for (int off = 32; off; off >>= 1) m = fmaxf(m, __shfl_xor(m, off));
    __shared__ float red[8];
    if (lane == 0) red[w] = m;
    __syncthreads();
    m = fmaxf(fmaxf(red[0], red[1]), fmaxf(red[2], red[3]));
    float s = 0.0f;
#pragma unroll
    for (int j = 0; j < 4; ++j) { x[j] = __expf(x[j] - m); s += x[j]; }
#pragma unroll
    for (int off = 32; off; off >>= 1) s += __shfl_xor(s, off);
    if (lane == 0) red[4 + w] = s;
    __syncthreads();
    s = red[4] + red[5] + red[6] + red[7];
    const float inv = 1.0f / s;
    h16x4 o;
#pragma unroll
    for (int j = 0; j < 4; ++j) o[j] = (h16)(x[j] * inv);
    *(h16x4*)&p[tid * 4] = o;
}

// ---------- launch ----------
extern "C" void kernel_launch(void* const* d_in, const int* in_sizes, int n_in,
                              void* d_out, int out_size, void* d_ws, size_t ws_size,
                              hipStream_t stream) {
    const float* q  = (const float*)d_in[0];
    const float* k  = (const float*)d_in[1];
    const float* v  = (const float*)d_in[2];
    const float* Wq = (const float*)d_in[3];
    const float* bq = (const float*)d_in[4];
    const float* Wk = (const float*)d_in[5];
    const float* bk = (const float*)d_in[6];
    const float* Wv = (const float*)d_in[7];
    const float* bv = (const float*)d_in[8];
    const float* Wo = (const float*)d_in[9];
    const float* bo = (const float*)d_in[10];
    float* out = (float*)d_out;

    // workspace layout: 224 MB total. V projection writes Vt (transposed
    // per (b,h)) directly, so no Vb buffer and no transpose kernel.
    char* ws = (char*)d_ws;
    const long MB = 1024L * 1024;
    h16* X  = (h16*)(ws + 0 * MB);     // 32 MB: converted q/k/v input (serial)
    h16* M  = (h16*)(ws + 32 * MB);    // 32 MB: effective weight (serial)
    h16* Qb = (h16*)(ws + 64 * MB);
    h16* Kb = (h16*)(ws + 96 * MB);
    h16* Vt = (h16*)(ws + 128 * MB);   // Vt[64 z][256 f][1024 t]
    h16* AO = (h16*)(ws + 160 * MB);
    h16* Sc = (h16*)(ws + 192 * MB);   // 32 MB score chunk (one batch, 16 heads)

    dim3 blk(256);
    dim3 g256(16, 16, 1);

    // Q projection: convert, build weight, GEMM (serially reusing X, M)
    k_f32_to_f16<<<16384, blk, 0, stream>>>(q, X);
    k_build_m<<<16384, blk, 0, stream>>>(Wq, M);
    k_gemm256<h16, false><<<g256, 512, 0, stream>>>(X, M, Qb, bq, 64);

    // K projection
    k_f32_to_f16<<<16384, blk, 0, stream>>>(k, X);
    k_build_m<<<16384, blk, 0, stream>>>(Wk, M);
    k_gemm256<h16, false><<<g256, 512, 0, stream>>>(X, M, Kb, bk, 64);

    // V projection (epilogue writes transposed Vt directly)
    k_f32_to_f16<<<16384, blk, 0, stream>>>(v, X);
    k_build_m<<<16384, blk, 0, stream>>>(Wv, M);
    k_gemm256<h16, true><<<g256, 512, 0, stream>>>(X, M, Vt, bv, 64);

    // attention, one batch (16 heads) at a time through the 32 MB score chunk
    for (int c = 0; c < 4; ++c) {
        const h16* Qc  = Qb + (long)c * 1024 * 4096;
        const h16* Kc  = Kb + (long)c * 1024 * 4096;
        const h16* VtC = Vt + (long)c * 16 * 256 * 1024;
        h16*       AOc = AO + (long)c * 1024 * 4096;

        // scores: Sc[zh][1024][1024] = (Q K^T)/16, fp16
        k_gemm_bt<h16, false><<<dim3(8, 8, 16), blk, 0, stream>>>(
            Qc, Kc, Sc, nullptr,
            4096, 4096, 1024,
            0, 256,                       // A: h-stride (256-col slices)
            0, 256,                       // B
            0, 1024L * 1024,              // C
            0.0625f, 8);

        // softmax rows in place (fp16)
        k_softmax<<<16384, blk, 0, stream>>>(Sc);

        // attn out: AOc[t][h*256+f] = P_zh . Vt_zh^T
        k_gemm_bt<h16, false><<<dim3(8, 2, 16), blk, 0, stream>>>(
            Sc, VtC, AOc, nullptr,
            1024, 1024, 4096,
            0, 1024L * 1024,              // A
            0, 256L * 1024,               // B
            0, 256,                       // C
            1.0f, 32);
    }

    // output projection: out = AO . Mo^T + bo (fp32 out)
    k_build_m<<<16384, blk, 0, stream>>>(Wo, M);
    k_gemm256<float, false><<<g256, 512, 0, stream>>>(AO, M, out, bo, 64);
}

// Round 11
// 865.421 us; speedup vs baseline: 1.1319x; 1.0103x over previous
//
#include <hip/hip_runtime.h>
#include <hip/hip_bf16.h>

// ---------- types ----------
typedef _Float16 h16;
typedef h16   h16x8 __attribute__((ext_vector_type(8)));
typedef h16   h16x4 __attribute__((ext_vector_type(4)));
typedef float f32x4 __attribute__((ext_vector_type(4)));

#define EMB 1024
#define ED4 4096L   // EMB*4 flattened feature dim

// ---------- async global->LDS (16B per lane, wave-uniform LDS base) ----------
__device__ __forceinline__ void gload_lds16(const void* g, void* l) {
    __builtin_amdgcn_global_load_lds(
        (__attribute__((address_space(1))) void*)g,
        (__attribute__((address_space(3))) void*)l,
        16, 0, 0);
}

// ---------- build effective block weight M[o*4+q][i*4+c] = s(q,c)*W[q^c][o][i], fp16 ----------
__global__ __launch_bounds__(256) void k_build_m(const float* __restrict__ W, h16* __restrict__ M) {
    int t = blockIdx.x * 256 + threadIdx.x;   // [0, 4096*1024)
    int i = t & 1023;
    int n = t >> 10;          // o*4+q
    int o = n >> 2, q = n & 3;
    // sign masks per q (bit c set => negative): q0:0xE q1:0x8 q2:0x2 q3:0x4
    unsigned packed = 0xEu | (0x8u << 4) | (0x2u << 8) | (0x4u << 12);
    unsigned sm = (packed >> (q * 4)) & 0xFu;
    h16x4 out;
#pragma unroll
    for (int c = 0; c < 4; ++c) {
        int d = q ^ c;
        float w = W[((long)d * EMB + o) * EMB + i];
        out[c] = (h16)(((sm >> c) & 1u) ? -w : w);
    }
    *(h16x4*)&M[(long)n * ED4 + i * 4] = out;
}

// ---------- fp32 -> fp16 convert (x inputs), 4 elems/thread ----------
__global__ __launch_bounds__(256) void k_f32_to_f16(const float* __restrict__ in, h16* __restrict__ out) {
    long i = ((long)blockIdx.x * 256 + threadIdx.x) * 4;
    float4 v = *(const float4*)(in + i);
    h16x4 o;
    o[0] = (h16)v.x; o[1] = (h16)v.y; o[2] = (h16)v.z; o[3] = (h16)v.w;
    *(h16x4*)(out + i) = o;
}

// =====================================================================
// 256x256-tile, BK=64, 2-phase GEMM (4096x4096x4096)
// r11 change vs round-10 green: phases merged 4 -> 2 (2 barriers/tile).
//   phA: ds_read A0(8)+B0(4)+B1(4); stage (t+1).A1,(t+1).B1;
//        lgkm0; MFMA quadrants (0,0),(0,1); BAR
//   phB: ds_read A1(8); stage (t+2).A0,(t+2).B0; vmcnt(4); lgkm0;
//        MFMA quadrants (1,0),(1,1); BAR
// Ledger (each wave drains own ds_reads via lgkmcnt(0) before MFMA and
// hence before the phase's post-barrier; every STAGE targets a region
// whose previous contents were last read >=1 post-barrier earlier):
//   (t+1).A1/B1 staged phA(t), other buffer; prev (t-1).A1 last read
//     phB(t-1), prev (t-1).B1 last read phA(t-1) -> >=1 barrier behind.
//   (t+2).A0/B0 staged phB(t), same buffer, disjoint from A1 being read;
//     prev (t).A0/B0 last read phA(t) -> 1 barrier behind.
// vmcnt (instruction-counted, 2 loads/STAGE): per tile phA=4, phB=4.
//   vmcnt(4)@phB(t) leaves only (t+2).A0/B0 in flight -> tile t+1 fully
//   landed. Prologue: 12 loads, vmcnt(4) -> tile 0 landed. vmcnt(0) at
//   t >= nt-2. Never drains to 0 mid-loop.
// VT=true: V-projection epilogue writes Vt[(b*16+h)][f][t] directly.
// =====================================================================
#define BAR() __builtin_amdgcn_s_barrier()
#define LGKM0() do { asm volatile("s_waitcnt lgkmcnt(0)" ::: "memory"); \
                     __builtin_amdgcn_sched_barrier(0); } while (0)
#define STAGE(matv, basev, row0v, tt, hh) do { \
    const h16* _src = (basev) + ((row0v) + (hh) * 128L) * 4096L + (long)(tt) * 64 + scol; \
    h16* _dst = &lds[(((tt) & 1) << 15) + (matv) * 16384 + (hh) * 8192 + w * 512]; \
    gload_lds16(_src, _dst); \
    gload_lds16(_src + 64 * 4096L, _dst + 4096); \
} while (0)
#define LDA_(mh, m, ks) (*(const h16x8*)&lds[cb + (mh) * 8192 + (wm * 64 + (m) * 16 + fr) * 64 + ((((ks) * 4 + kq) ^ fr7) << 3)])
#define LDB_(nh, n, ks) (*(const h16x8*)&lds[cb + 16384 + (nh) * 8192 + (wn * 32 + (n) * 16 + fr) * 64 + ((((ks) * 4 + kq) ^ fr7) << 3)])
#define MFMA_Q(MH, NH, BF) do { \
    __builtin_amdgcn_s_setprio(1); \
    _Pragma("unroll") \
    for (int m = 0; m < 4; ++m) \
        _Pragma("unroll") \
        for (int n = 0; n < 2; ++n) { \
            acc[MH][NH][m][n] = __builtin_amdgcn_mfma_f32_16x16x32_f16(af[m][0], BF[n][0], acc[MH][NH][m][n], 0, 0, 0); \
            acc[MH][NH][m][n] = __builtin_amdgcn_mfma_f32_16x16x32_f16(af[m][1], BF[n][1], acc[MH][NH][m][n], 0, 0, 0); \
        } \
    __builtin_amdgcn_s_setprio(0); \
} while (0)

template <typename OUT_T, bool VT>
__global__ __launch_bounds__(512, 2) void k_gemm256(
    const h16* __restrict__ A, const h16* __restrict__ B,
    OUT_T* __restrict__ C, const float* __restrict__ bias, int nt)
{
    __shared__ __align__(16) h16 lds[65536];   // 128 KiB

    const int tid = threadIdx.x;
    const int w  = tid >> 6, l = tid & 63;
    const int wm = w >> 2, wn = w & 3;          // wave grid 2x4 within each quadrant
    const int fr = l & 15, fr7 = l & 7, kq = l >> 4;

    // staging: thread covers 16B; srow in [0,64) per gload, swizzled col
    const int srow = w * 8 + (l >> 3);
    const int scol = ((l & 7) ^ ((l >> 3) & 7)) << 3;
    const long arow0 = (long)blockIdx.x * 256 + srow;
    const long brow0 = (long)blockIdx.y * 256 + srow;

    f32x4 acc[2][2][4][2] = {};   // [mh][nh][m][n]

    // prologue: 0.A0 0.B0 0.A1 0.B1 1.A0 1.B0 (12 loads); vmcnt(4) -> tile0 landed
    STAGE(0, A, arow0, 0, 0);
    STAGE(1, B, brow0, 0, 0);
    STAGE(0, A, arow0, 0, 1);
    STAGE(1, B, brow0, 0, 1);
    STAGE(0, A, arow0, 1, 0);
    STAGE(1, B, brow0, 1, 0);
    asm volatile("s_waitcnt vmcnt(4)" ::: "memory");
    __builtin_amdgcn_sched_barrier(0);
    BAR();

    for (int t = 0; t < nt; ++t) {
        const int cb = (t & 1) << 15;
        h16x8 af[4][2], b0[2][2], b1[2][2];

        // ---- phase A: quadrants (0,0)+(0,1) — read A0,B0,B1; stage (t+1).A1,B1 ----
#pragma unroll
        for (int m = 0; m < 4; ++m) { af[m][0] = LDA_(0, m, 0); af[m][1] = LDA_(0, m, 1); }
#pragma unroll
        for (int n = 0; n < 2; ++n) { b0[n][0] = LDB_(0, n, 0); b0[n][1] = LDB_(0, n, 1); }
#pragma unroll
        for (int n = 0; n < 2; ++n) { b1[n][0] = LDB_(1, n, 0); b1[n][1] = LDB_(1, n, 1); }
        if (t + 1 < nt) {
            STAGE(0, A, arow0, t + 1, 1);
            STAGE(1, B, brow0, t + 1, 1);
        }
        LGKM0();
        MFMA_Q(0, 0, b0);
        MFMA_Q(0, 1, b1);
        BAR();

        // ---- phase B: quadrants (1,0)+(1,1) — read A1; stage (t+2).A0,B0; drain ----
#pragma unroll
        for (int m = 0; m < 4; ++m) { af[m][0] = LDA_(1, m, 0); af[m][1] = LDA_(1, m, 1); }
        if (t + 2 < nt) {
            STAGE(0, A, arow0, t + 2, 0);
            STAGE(1, B, brow0, t + 2, 0);
        }
        if (t < nt - 2) { asm volatile("s_waitcnt vmcnt(4)" ::: "memory"); }
        else            { asm volatile("s_waitcnt vmcnt(0)" ::: "memory"); }
        __builtin_amdgcn_sched_barrier(0);
        LGKM0();
        MFMA_Q(1, 0, b0);
        MFMA_Q(1, 1, b1);
        BAR();
    }

    // epilogue: row = bx*256 + mh*128 + wm*64 + m*16 + kq*4 + j
    //           col = by*256 + nh*128 + wn*32 + n*16 + fr
    const long row00 = (long)blockIdx.x * 256 + wm * 64 + kq * 4;
    const int  col00 = (int)blockIdx.y * 256 + wn * 32 + fr;
#pragma unroll
    for (int mh = 0; mh < 2; ++mh)
#pragma unroll
        for (int nh = 0; nh < 2; ++nh)
#pragma unroll
            for (int n = 0; n < 2; ++n) {
                const int col = col00 + nh * 128 + n * 16;
                const float bv = bias[col];
#pragma unroll
                for (int m = 0; m < 4; ++m) {
                    const long r0 = row00 + mh * 128 + m * 16;
                    if constexpr (VT) {
                        // Vt[(r>>10)*16 + (col>>8)][col&255][r&1023], r0 % 4 == 0
                        h16x4 o;
#pragma unroll
                        for (int j = 0; j < 4; ++j) o[j] = (h16)(acc[mh][nh][m][n][j] + bv);
                        const long zidx = (r0 >> 10) * 16 + (col >> 8);
                        *(h16x4*)((h16*)C + zidx * 262144L + (long)(col & 255) * 1024 + (r0 & 1023)) = o;
                    } else {
#pragma unroll
                        for (int j = 0; j < 4; ++j)
                            C[(r0 + j) * 4096L + col] = (OUT_T)(acc[mh][nh][m][n][j] + bv);
                    }
                }
            }
}

// ---------- GEMM: C[m][n] = alpha * sum_k A[m][k]*B[n][k] (+ bias[n]) ----------
// 128x128 tile, BK=32 (m97 structure) — used for the attention GEMMs.
// LDS XOR-swizzle (r9): LDS row r holds global 16B-slot s at slot s ^ ((r>>1)&3).
template <typename OUT_T, bool HAS_BIAS>
__global__ __launch_bounds__(256) void k_gemm_bt(
    const h16* __restrict__ A, const h16* __restrict__ B,
    OUT_T* __restrict__ C, const float* __restrict__ bias,
    int lda, int ldb, int ldc,
    long sAb, long sAh, long sBb, long sBh, long sCb, long sCh,
    float alpha, int kIters)
{
    __shared__ __align__(16) h16 As[128 * 32];
    __shared__ __align__(16) h16 Bs[128 * 32];

    const int z = blockIdx.z, zb = z >> 4, zh = z & 15;
    const h16* Ab = A + zb * sAb + zh * sAh + (long)blockIdx.x * 128 * lda;
    const h16* Bb = B + zb * sBb + zh * sBh + (long)blockIdx.y * 128 * ldb;

    const int tid = threadIdx.x, w = tid >> 6, lane = tid & 63;
    const int wr = (w >> 1) * 64, wc = (w & 1) * 64;
    const int scol = (((lane & 3) ^ ((lane >> 3) & 3)) * 8);   // swizzled global src slot
    const int srow = lane >> 2;
    const int fr   = lane & 15;
    const int koff = (((lane >> 4) ^ ((fr >> 1) & 3)) * 8);    // swizzled LDS read slot

    f32x4 acc[4][4] = {};

    for (int kt = 0; kt < kIters; ++kt) {
        const int k0 = kt * 32;
#pragma unroll
        for (int j = 0; j < 2; ++j) {
            const int ca  = w * 2 + j;
            const int row = ca * 16 + srow;
            gload_lds16(Ab + (long)row * lda + k0 + scol, &As[ca * 512]);
            gload_lds16(Bb + (long)row * ldb + k0 + scol, &Bs[ca * 512]);
        }
        __syncthreads();

        h16x8 af[4], bfr[4];
#pragma unroll
        for (int m = 0; m < 4; ++m)
            af[m] = *(const h16x8*)&As[(wr + m * 16 + fr) * 32 + koff];
#pragma unroll
        for (int n = 0; n < 4; ++n)
            bfr[n] = *(const h16x8*)&Bs[(wc + n * 16 + fr) * 32 + koff];
        __syncthreads();

#pragma unroll
        for (int m = 0; m < 4; ++m)
#pragma unroll
            for (int n = 0; n < 4; ++n)
                acc[m][n] = __builtin_amdgcn_mfma_f32_16x16x32_f16(af[m], bfr[n], acc[m][n], 0, 0, 0);
    }

    OUT_T* Cb = C + zb * sCb + zh * sCh;
    const long rbase = (long)blockIdx.x * 128 + wr + (lane >> 4) * 4;
    const int  cbase = blockIdx.y * 128 + wc + fr;
#pragma unroll
    for (int n = 0; n < 4; ++n) {
        const int col = cbase + n * 16;
        const float bv = HAS_BIAS ? bias[col] : 0.0f;
#pragma unroll
        for (int m = 0; m < 4; ++m) {
            const long row0 = rbase + m * 16;
#pragma unroll
            for (int j = 0; j < 4; ++j) {
                float vv = acc[m][n][j] * alpha + bv;
                Cb[(row0 + j) * ldc + col] = (OUT_T)vv;
            }
        }
    }
}

// ---------- row softmax over S[row][1024] fp16 in place ----------
__global__ __launch_bounds__(256) void k_softmax(h16* __restrict__ S) {
    const long row = blockIdx.x;
    h16* p = S + row * 1024;
    const int tid = threadIdx.x, w = tid >> 6, lane = tid & 63;
    h16x4 xi = *(const h16x4*)&p[tid * 4];
    float x[4];
#pragma unroll
    for (int j = 0; j < 4; ++j) x[j] = (float)xi[j];
    float m = fmaxf(fmaxf(x[0], x[1]), fmaxf(x[2], x[3]));
#pragma unroll
    for (int off = 32; off; off >>= 1) m = fmaxf(m, __shfl_xor(m, off));
    __shared__ float red[8];
    if (lane == 0) red[w] = m;
    __syncthreads();
    m = fmaxf(fmaxf(red[0], red[1]), fmaxf(red[2], red[3]));
    float s = 0.0f;
#pragma unroll
    for (int j = 0; j < 4; ++j) { x[j] = __expf(x[j] - m); s += x[j]; }
#pragma unroll
    for (int off = 32; off; off >>= 1) s += __shfl_xor(s, off);
    if (lane == 0) red[4 + w] = s;
    __syncthreads();
    s = red[4] + red[5] + red[6] + red[7];
    const float inv = 1.0f / s;
    h16x4 o;
#pragma unroll
    for (int j = 0; j < 4; ++j) o[j] = (h16)(x[j] * inv);
    *(h16x4*)&p[tid * 4] = o;
}

// ---------- launch ----------
extern "C" void kernel_launch(void* const* d_in, const int* in_sizes, int n_in,
                              void* d_out, int out_size, void* d_ws, size_t ws_size,
                              hipStream_t stream) {
    const float* q  = (const float*)d_in[0];
    const float* k  = (const float*)d_in[1];
    const float* v  = (const float*)d_in[2];
    const float* Wq = (const float*)d_in[3];
    const float* bq = (const float*)d_in[4];
    const float* Wk = (const float*)d_in[5];
    const float* bk = (const float*)d_in[6];
    const float* Wv = (const float*)d_in[7];
    const float* bv = (const float*)d_in[8];
    const float* Wo = (const float*)d_in[9];
    const float* bo = (const float*)d_in[10];
    float* out = (float*)d_out;

    // workspace layout: 224 MB total. V projection writes Vt (transposed
    // per (b,h)) directly, so no Vb buffer and no transpose kernel.
    char* ws = (char*)d_ws;
    const long MB = 1024L * 1024;
    h16* X  = (h16*)(ws + 0 * MB);     // 32 MB: converted q/k/v input (serial)
    h16* M  = (h16*)(ws + 32 * MB);    // 32 MB: effective weight (serial)
    h16* Qb = (h16*)(ws + 64 * MB);
    h16* Kb = (h16*)(ws + 96 * MB);
    h16* Vt = (h16*)(ws + 128 * MB);   // Vt[64 z][256 f][1024 t]
    h16* AO = (h16*)(ws + 160 * MB);
    h16* Sc = (h16*)(ws + 192 * MB);   // 32 MB score chunk (one batch, 16 heads)

    dim3 blk(256);
    dim3 g256(16, 16, 1);

    // Q projection: convert, build weight, GEMM (serially reusing X, M)
    k_f32_to_f16<<<16384, blk, 0, stream>>>(q, X);
    k_build_m<<<16384, blk, 0, stream>>>(Wq, M);
    k_gemm256<h16, false><<<g256, 512, 0, stream>>>(X, M, Qb, bq, 64);

    // K projection
    k_f32_to_f16<<<16384, blk, 0, stream>>>(k, X);
    k_build_m<<<16384, blk, 0, stream>>>(Wk, M);
    k_gemm256<h16, false><<<g256, 512, 0, stream>>>(X, M, Kb, bk, 64);

    // V projection (epilogue writes transposed Vt directly)
    k_f32_to_f16<<<16384, blk, 0, stream>>>(v, X);
    k_build_m<<<16384, blk, 0, stream>>>(Wv, M);
    k_gemm256<h16, true><<<g256, 512, 0, stream>>>(X, M, Vt, bv, 64);

    // attention, one batch (16 heads) at a time through the 32 MB score chunk
    for (int c = 0; c < 4; ++c) {
        const h16* Qc  = Qb + (long)c * 1024 * 4096;
        const h16* Kc  = Kb + (long)c * 1024 * 4096;
        const h16* VtC = Vt + (long)c * 16 * 256 * 1024;
        h16*       AOc = AO + (long)c * 1024 * 4096;

        // scores: Sc[zh][1024][1024] = (Q K^T)/16, fp16
        k_gemm_bt<h16, false><<<dim3(8, 8, 16), blk, 0, stream>>>(
            Qc, Kc, Sc, nullptr,
            4096, 4096, 1024,
            0, 256,                       // A: h-stride (256-col slices)
            0, 256,                       // B
            0, 1024L * 1024,              // C
            0.0625f, 8);

        // softmax rows in place (fp16)
        k_softmax<<<16384, blk, 0, stream>>>(Sc);

        // attn out: AOc[t][h*256+f] = P_zh . Vt_zh^T
        k_gemm_bt<h16, false><<<dim3(8, 2, 16), blk, 0, stream>>>(
            Sc, VtC, AOc, nullptr,
            1024, 1024, 4096,
            0, 1024L * 1024,              // A
            0, 256L * 1024,               // B
            0, 256,                       // C
            1.0f, 32);
    }

    // output projection: out = AO . Mo^T + bo (fp32 out)
    k_build_m<<<16384, blk, 0, stream>>>(Wo, M);
    k_gemm256<float, false><<<g256, 512, 0, stream>>>(AO, M, out, bo, 64);
}